// Round 1
// baseline (515.935 us; speedup 1.0000x reference)
//
#include <hip/hip_runtime.h>
#include <cstdint>
#include <cstddef>

#define D_MODEL 1024
#define N_EXPERTS 8
#define FFN_H 2048
#define N_TOK 4096
#define CAP 2048

typedef float f32x4 __attribute__((ext_vector_type(4)));
typedef __bf16 bf16x8 __attribute__((ext_vector_type(8)));

// ---- workspace layout (bytes) ----
static constexpr size_t XB_OFF   = 0;                          // [N_TOK][D] bf16
static constexpr size_t W1B_OFF  = XB_OFF  + (size_t)N_TOK * D_MODEL * 2;        // [E][H][D] bf16
static constexpr size_t W2B_OFF  = W1B_OFF + (size_t)N_EXPERTS * FFN_H * D_MODEL * 2; // [E][D][H] bf16
static constexpr size_t HBUF_OFF = W2B_OFF + (size_t)N_EXPERTS * D_MODEL * FFN_H * 2; // [E][CAP][H] bf16
static constexpr size_t CNT_OFF  = HBUF_OFF + (size_t)N_EXPERTS * CAP * FFN_H * 2;    // [E] int
static constexpr size_t PSUM_OFF = CNT_OFF + 32;               // [E] float
static constexpr size_t TOK_OFF  = PSUM_OFF + 32;              // [E][CAP] int
static constexpr size_t WT_OFF   = TOK_OFF + (size_t)N_EXPERTS * CAP * 4; // [E][CAP] float

// ---------------- fp32 -> bf16 conversion, 8 elems/thread ----------------
__global__ __launch_bounds__(256) void cvt_bf16_kernel(const float* __restrict__ src,
                                                       __bf16* __restrict__ dst) {
    size_t i = ((size_t)blockIdx.x * 256 + threadIdx.x) * 8;
    float4 a = *reinterpret_cast<const float4*>(src + i);
    float4 b = *reinterpret_cast<const float4*>(src + i + 4);
    bf16x8 r;
    r[0] = (__bf16)a.x; r[1] = (__bf16)a.y; r[2] = (__bf16)a.z; r[3] = (__bf16)a.w;
    r[4] = (__bf16)b.x; r[5] = (__bf16)b.y; r[6] = (__bf16)b.z; r[7] = (__bf16)b.w;
    *reinterpret_cast<bf16x8*>(dst + i) = r;
}

// ---------------- router: one wave per token ----------------
__global__ __launch_bounds__(256) void router_kernel(const float* __restrict__ x,
                                                     const float* __restrict__ rw,
                                                     int* __restrict__ counts,
                                                     float* __restrict__ psum,
                                                     int* __restrict__ tok_list,
                                                     float* __restrict__ wt_list) {
    __shared__ float rws[N_EXPERTS * D_MODEL];
    __shared__ float pacc[N_EXPERTS];
    int tid = threadIdx.x;
    for (int i = tid * 4; i < N_EXPERTS * D_MODEL; i += 256 * 4)
        *reinterpret_cast<float4*>(&rws[i]) = *reinterpret_cast<const float4*>(&rw[i]);
    if (tid < N_EXPERTS) pacc[tid] = 0.f;
    __syncthreads();

    int wave = tid >> 6, lane = tid & 63;
    int t = blockIdx.x * 4 + wave;
    const float* xr = x + (size_t)t * D_MODEL;
    float acc[8] = {0, 0, 0, 0, 0, 0, 0, 0};
#pragma unroll
    for (int i = 0; i < D_MODEL / 64; ++i) {
        float xv = xr[lane + 64 * i];
#pragma unroll
        for (int e = 0; e < 8; ++e) acc[e] += xv * rws[e * D_MODEL + lane + 64 * i];
    }
    float logit[8];
#pragma unroll
    for (int e = 0; e < 8; ++e) {
        float v = acc[e];
        for (int off = 32; off; off >>= 1) v += __shfl_xor(v, off);
        logit[e] = v;
    }
    // softmax over 8
    float mx = logit[0];
#pragma unroll
    for (int e = 1; e < 8; ++e) mx = fmaxf(mx, logit[e]);
    float p[8], s = 0.f;
#pragma unroll
    for (int e = 0; e < 8; ++e) { p[e] = expf(logit[e] - mx); s += p[e]; }
    float inv = 1.f / s;
#pragma unroll
    for (int e = 0; e < 8; ++e) p[e] *= inv;
    // top-2 (first index wins ties, matching lax.top_k)
    int e0 = 0; float p0 = p[0];
#pragma unroll
    for (int e = 1; e < 8; ++e) if (p[e] > p0) { p0 = p[e]; e0 = e; }
    int e1 = -1; float p1 = -1.f;
#pragma unroll
    for (int e = 0; e < 8; ++e) if (e != e0 && p[e] > p1) { p1 = p[e]; e1 = e; }
    float invw = 1.f / (p0 + p1);

    if (lane == 0) {
        int pos0 = atomicAdd(&counts[e0], 1);
        if (pos0 < CAP) { tok_list[e0 * CAP + pos0] = t; wt_list[e0 * CAP + pos0] = p0 * invw; }
        int pos1 = atomicAdd(&counts[e1], 1);
        if (pos1 < CAP) { tok_list[e1 * CAP + pos1] = t; wt_list[e1 * CAP + pos1] = p1 * invw; }
#pragma unroll
        for (int e = 0; e < 8; ++e) atomicAdd(&pacc[e], p[e]);
    }
    __syncthreads();
    if (tid < 8) atomicAdd(&psum[tid], pacc[tid]);
}

// ---------------- aux loss ----------------
__global__ void aux_kernel(const int* __restrict__ counts, const float* __restrict__ psum,
                           float* __restrict__ out_aux) {
    int lane = threadIdx.x;
    float v = 0.f;
    if (lane < 8)
        v = ((float)counts[lane] / (float)(N_TOK * 2)) * (psum[lane] / (float)N_TOK);
    for (int off = 32; off; off >>= 1) v += __shfl_xor(v, off);
    if (lane == 0) *out_aux = 8.f * v;
}

// ---------------- grouped GEMM: pass1 (x@w1^T, silu) / pass2 (h@w2^T, scatter) ----------------
template <int KDIM, bool PASS2>
__global__ __launch_bounds__(256) void ffn_kernel(const __bf16* __restrict__ A_base,
                                                  const __bf16* __restrict__ B_base,
                                                  const float* __restrict__ bias,
                                                  const int* __restrict__ counts,
                                                  const int* __restrict__ tok_list,
                                                  const float* __restrict__ wt_list,
                                                  __bf16* __restrict__ Hbuf,
                                                  float* __restrict__ out) {
    constexpr int BROWS = PASS2 ? D_MODEL : FFN_H;
    int e = blockIdx.z;
    int cnt = min(counts[e], CAP);
    int m0 = blockIdx.y * 64;
    if (m0 >= cnt) return;
    int n0 = blockIdx.x * 64;

    __shared__ __bf16 s_a[64 * 32];
    __shared__ __bf16 s_b[64 * 32];
    __shared__ int s_tok[64];
    __shared__ float s_wt[64];

    int tid = threadIdx.x;
    if (tid < 64) {
        int slot = min(m0 + tid, cnt - 1);
        s_tok[tid] = tok_list[e * CAP + slot];
        s_wt[tid] = wt_list[e * CAP + slot];
    }
    __syncthreads();

    int arow = tid >> 2;
    int acol = (tid & 3) * 8;
    const __bf16* a_src;
    if (PASS2) {
        int slot = min(m0 + arow, cnt - 1);
        a_src = A_base + ((size_t)e * CAP + slot) * KDIM + acol;
    } else {
        a_src = A_base + (size_t)s_tok[arow] * KDIM + acol;
    }
    const __bf16* b_src = B_base + ((size_t)e * BROWS + n0 + arow) * KDIM + acol;

    int wv = tid >> 6, lane = tid & 63;
    int wm = wv >> 1, wn = wv & 1;
    int lm = lane & 15, q = lane >> 4;
    const int a_off = (wm * 32 + lm) * 32 + q * 8;
    const int b_off = (wn * 32 + lm) * 32 + q * 8;

    f32x4 acc[2][2] = {};
    for (int k0 = 0; k0 < KDIM; k0 += 32) {
        uint4 av = *reinterpret_cast<const uint4*>(a_src + k0);
        uint4 bv = *reinterpret_cast<const uint4*>(b_src + k0);
        *reinterpret_cast<uint4*>(&s_a[arow * 32 + acol]) = av;
        *reinterpret_cast<uint4*>(&s_b[arow * 32 + acol]) = bv;
        __syncthreads();
        bf16x8 af0 = *reinterpret_cast<const bf16x8*>(&s_a[a_off]);
        bf16x8 af1 = *reinterpret_cast<const bf16x8*>(&s_a[a_off + 16 * 32]);
        bf16x8 bf0 = *reinterpret_cast<const bf16x8*>(&s_b[b_off]);
        bf16x8 bf1 = *reinterpret_cast<const bf16x8*>(&s_b[b_off + 16 * 32]);
        acc[0][0] = __builtin_amdgcn_mfma_f32_16x16x32_bf16(af0, bf0, acc[0][0], 0, 0, 0);
        acc[0][1] = __builtin_amdgcn_mfma_f32_16x16x32_bf16(af0, bf1, acc[0][1], 0, 0, 0);
        acc[1][0] = __builtin_amdgcn_mfma_f32_16x16x32_bf16(af1, bf0, acc[1][0], 0, 0, 0);
        acc[1][1] = __builtin_amdgcn_mfma_f32_16x16x32_bf16(af1, bf1, acc[1][1], 0, 0, 0);
        __syncthreads();
    }

#pragma unroll
    for (int rn = 0; rn < 2; ++rn) {
        int col = wn * 32 + rn * 16 + lm;
        int n = n0 + col;
        float bv = bias[e * BROWS + n];
#pragma unroll
        for (int rm = 0; rm < 2; ++rm) {
#pragma unroll
            for (int i = 0; i < 4; ++i) {
                int row = wm * 32 + rm * 16 + q * 4 + i;
                int slot = m0 + row;
                if (slot < cnt) {
                    float v = acc[rm][rn][i] + bv;
                    if (!PASS2) {
                        float sv = v / (1.f + __expf(-v));
                        Hbuf[((size_t)e * CAP + slot) * FFN_H + n] = (__bf16)sv;
                    } else {
                        atomicAdd(&out[(size_t)s_tok[row] * D_MODEL + n], s_wt[row] * v);
                    }
                }
            }
        }
    }
}

extern "C" void kernel_launch(void* const* d_in, const int* in_sizes, int n_in,
                              void* d_out, int out_size, void* d_ws, size_t ws_size,
                              hipStream_t stream) {
    const float* x  = (const float*)d_in[0];
    const float* rw = (const float*)d_in[1];
    const float* w1 = (const float*)d_in[2];
    const float* b1 = (const float*)d_in[3];
    const float* w2 = (const float*)d_in[4];
    const float* b2 = (const float*)d_in[5];
    float* out = (float*)d_out;

    char* ws = (char*)d_ws;
    __bf16* xb   = (__bf16*)(ws + XB_OFF);
    __bf16* w1b  = (__bf16*)(ws + W1B_OFF);
    __bf16* w2b  = (__bf16*)(ws + W2B_OFF);
    __bf16* hbuf = (__bf16*)(ws + HBUF_OFF);
    int*   counts = (int*)(ws + CNT_OFF);
    float* psum   = (float*)(ws + PSUM_OFF);
    int*   tok    = (int*)(ws + TOK_OFF);
    float* wt     = (float*)(ws + WT_OFF);

    // zero output (poisoned 0xAA) and router accumulators
    hipMemsetAsync(out, 0, (size_t)out_size * sizeof(float), stream);
    hipMemsetAsync(ws + CNT_OFF, 0, 64, stream);

    // fp32 -> bf16 conversions
    {
        size_t n = (size_t)N_TOK * D_MODEL;
        cvt_bf16_kernel<<<(int)(n / 8 / 256), 256, 0, stream>>>(x, xb);
    }
    {
        size_t n = (size_t)N_EXPERTS * FFN_H * D_MODEL;
        cvt_bf16_kernel<<<(int)(n / 8 / 256), 256, 0, stream>>>(w1, w1b);
        cvt_bf16_kernel<<<(int)(n / 8 / 256), 256, 0, stream>>>(w2, w2b);
    }

    router_kernel<<<N_TOK / 4, 256, 0, stream>>>(x, rw, counts, psum, tok, wt);

    ffn_kernel<D_MODEL, false><<<dim3(FFN_H / 64, CAP / 64, N_EXPERTS), 256, 0, stream>>>(
        xb, w1b, b1, counts, tok, wt, hbuf, nullptr);
    ffn_kernel<FFN_H, true><<<dim3(D_MODEL / 64, CAP / 64, N_EXPERTS), 256, 0, stream>>>(
        hbuf, w2b, b2, counts, tok, wt, nullptr, out);

    aux_kernel<<<1, 64, 0, stream>>>(counts, psum, out + (size_t)N_TOK * D_MODEL);
}

// Round 2
// 466.775 us; speedup vs baseline: 1.1053x; 1.1053x over previous
//
#include <hip/hip_runtime.h>
#include <cstdint>
#include <cstddef>

#define D_MODEL 1024
#define N_EXPERTS 8
#define FFN_H 2048
#define N_TOK 4096
#define CAP 2048

typedef float f32x4 __attribute__((ext_vector_type(4)));
typedef __bf16 bf16x8 __attribute__((ext_vector_type(8)));

// ---- workspace layout (bytes) ----
static constexpr size_t XB_OFF   = 0;                          // [N_TOK][D] bf16
static constexpr size_t W1B_OFF  = XB_OFF  + (size_t)N_TOK * D_MODEL * 2;        // [E][H][D] bf16
static constexpr size_t W2B_OFF  = W1B_OFF + (size_t)N_EXPERTS * FFN_H * D_MODEL * 2; // [E][D][H] bf16
static constexpr size_t HBUF_OFF = W2B_OFF + (size_t)N_EXPERTS * D_MODEL * FFN_H * 2; // [E][CAP][H] bf16
static constexpr size_t CNT_OFF  = HBUF_OFF + (size_t)N_EXPERTS * CAP * FFN_H * 2;    // [E] int
static constexpr size_t PSUM_OFF = CNT_OFF + 32;               // [E] float
static constexpr size_t TOK_OFF  = PSUM_OFF + 32;              // [E][CAP] int
static constexpr size_t WT_OFF   = TOK_OFF + (size_t)N_EXPERTS * CAP * 4; // [E][CAP] float

// async global->LDS, 16 B per lane; LDS dest = wave-uniform base + lane*16
__device__ __forceinline__ void async_ld16(const void* g, void* l) {
    __builtin_amdgcn_global_load_lds(
        (const __attribute__((address_space(1))) unsigned int*)g,
        (__attribute__((address_space(3))) unsigned int*)l, 16, 0, 0);
}

// ---------------- fp32 -> bf16 conversion, 8 elems/thread ----------------
__global__ __launch_bounds__(256) void cvt_bf16_kernel(const float* __restrict__ src,
                                                       __bf16* __restrict__ dst) {
    size_t i = ((size_t)blockIdx.x * 256 + threadIdx.x) * 8;
    float4 a = *reinterpret_cast<const float4*>(src + i);
    float4 b = *reinterpret_cast<const float4*>(src + i + 4);
    bf16x8 r;
    r[0] = (__bf16)a.x; r[1] = (__bf16)a.y; r[2] = (__bf16)a.z; r[3] = (__bf16)a.w;
    r[4] = (__bf16)b.x; r[5] = (__bf16)b.y; r[6] = (__bf16)b.z; r[7] = (__bf16)b.w;
    *reinterpret_cast<bf16x8*>(dst + i) = r;
}

// ---------------- router: one wave per token ----------------
__global__ __launch_bounds__(256) void router_kernel(const float* __restrict__ x,
                                                     const float* __restrict__ rw,
                                                     int* __restrict__ counts,
                                                     float* __restrict__ psum,
                                                     int* __restrict__ tok_list,
                                                     float* __restrict__ wt_list) {
    __shared__ float rws[N_EXPERTS * D_MODEL];
    __shared__ float pacc[N_EXPERTS];
    int tid = threadIdx.x;
    for (int i = tid * 4; i < N_EXPERTS * D_MODEL; i += 256 * 4)
        *reinterpret_cast<float4*>(&rws[i]) = *reinterpret_cast<const float4*>(&rw[i]);
    if (tid < N_EXPERTS) pacc[tid] = 0.f;
    __syncthreads();

    int wave = tid >> 6, lane = tid & 63;
    int t = blockIdx.x * 4 + wave;
    const float* xr = x + (size_t)t * D_MODEL;
    float acc[8] = {0, 0, 0, 0, 0, 0, 0, 0};
#pragma unroll
    for (int i = 0; i < D_MODEL / 64; ++i) {
        float xv = xr[lane + 64 * i];
#pragma unroll
        for (int e = 0; e < 8; ++e) acc[e] += xv * rws[e * D_MODEL + lane + 64 * i];
    }
    float logit[8];
#pragma unroll
    for (int e = 0; e < 8; ++e) {
        float v = acc[e];
        for (int off = 32; off; off >>= 1) v += __shfl_xor(v, off);
        logit[e] = v;
    }
    float mx = logit[0];
#pragma unroll
    for (int e = 1; e < 8; ++e) mx = fmaxf(mx, logit[e]);
    float p[8], s = 0.f;
#pragma unroll
    for (int e = 0; e < 8; ++e) { p[e] = expf(logit[e] - mx); s += p[e]; }
    float inv = 1.f / s;
#pragma unroll
    for (int e = 0; e < 8; ++e) p[e] *= inv;
    int e0 = 0; float p0 = p[0];
#pragma unroll
    for (int e = 1; e < 8; ++e) if (p[e] > p0) { p0 = p[e]; e0 = e; }
    int e1 = -1; float p1 = -1.f;
#pragma unroll
    for (int e = 0; e < 8; ++e) if (e != e0 && p[e] > p1) { p1 = p[e]; e1 = e; }
    float invw = 1.f / (p0 + p1);

    if (lane == 0) {
        int pos0 = atomicAdd(&counts[e0], 1);
        if (pos0 < CAP) { tok_list[e0 * CAP + pos0] = t; wt_list[e0 * CAP + pos0] = p0 * invw; }
        int pos1 = atomicAdd(&counts[e1], 1);
        if (pos1 < CAP) { tok_list[e1 * CAP + pos1] = t; wt_list[e1 * CAP + pos1] = p1 * invw; }
#pragma unroll
        for (int e = 0; e < 8; ++e) atomicAdd(&pacc[e], p[e]);
    }
    __syncthreads();
    if (tid < 8) atomicAdd(&psum[tid], pacc[tid]);
}

// ---------------- aux loss ----------------
__global__ void aux_kernel(const int* __restrict__ counts, const float* __restrict__ psum,
                           float* __restrict__ out_aux) {
    int lane = threadIdx.x;
    float v = 0.f;
    if (lane < 8)
        v = ((float)counts[lane] / (float)(N_TOK * 2)) * (psum[lane] / (float)N_TOK);
    for (int off = 32; off; off >>= 1) v += __shfl_xor(v, off);
    if (lane == 0) *out_aux = 8.f * v;
}

// ---------------- grouped GEMM, 128x128 tile, global_load_lds staging ----------------
// pass1: silu(x@w1^T + b1) -> Hbuf bf16 ; pass2: (h@w2^T + b2)*wt scattered to out
template <int KDIM, bool PASS2>
__global__ __launch_bounds__(256) void ffn_kernel(const __bf16* __restrict__ A_base,
                                                  const __bf16* __restrict__ B_base,
                                                  const float* __restrict__ bias,
                                                  const int* __restrict__ counts,
                                                  const int* __restrict__ tok_list,
                                                  const float* __restrict__ wt_list,
                                                  __bf16* __restrict__ Hbuf,
                                                  float* __restrict__ out) {
    constexpr int BROWS = PASS2 ? D_MODEL : FFN_H;
    int e = blockIdx.z;
    int cnt = min(counts[e], CAP);
    int m0 = blockIdx.y * 128;
    if (m0 >= cnt) return;
    int n0 = blockIdx.x * 128;

    __shared__ __bf16 s_a[128 * 32];   // 8 KB, row-major, NO pad (global_load_lds)
    __shared__ __bf16 s_b[128 * 32];   // 8 KB
    __shared__ int s_tok[128];
    __shared__ float s_wt[128];

    int tid = threadIdx.x;
    if (tid < 128) {
        int slot = min(m0 + tid, cnt - 1);
        s_tok[tid] = tok_list[e * CAP + slot];
        s_wt[tid] = wt_list[e * CAP + slot];
    }
    __syncthreads();

    // staging: thread stages rows r0=tid>>2 and r0+64, 16 B at col (tid&3)*8
    int colk = (tid & 3) * 8;
    const __bf16 *a_src0, *a_src1;
    if (PASS2) {
        int s0 = min(m0 + (tid >> 2), cnt - 1);
        int s1 = min(m0 + 64 + (tid >> 2), cnt - 1);
        a_src0 = A_base + ((size_t)e * CAP + s0) * KDIM + colk;
        a_src1 = A_base + ((size_t)e * CAP + s1) * KDIM + colk;
    } else {
        a_src0 = A_base + (size_t)s_tok[tid >> 2] * KDIM + colk;
        a_src1 = A_base + (size_t)s_tok[64 + (tid >> 2)] * KDIM + colk;
    }
    const __bf16* b_src0 = B_base + ((size_t)e * BROWS + n0 + (tid >> 2)) * KDIM + colk;
    const __bf16* b_src1 = b_src0 + (size_t)64 * KDIM;

    // wave-uniform LDS staging bases (HW adds lane*16)
    char* lds_a = (char*)s_a + (tid >> 6) * 1024;
    char* lds_b = (char*)s_b + (tid >> 6) * 1024;

    int wv = tid >> 6, lane = tid & 63;
    int wm = wv >> 1, wn = wv & 1;
    int lm = lane & 15, q = lane >> 4;
    int a_base = (wm * 64 + lm) * 32 + q * 8;
    int b_base = (wn * 64 + lm) * 32 + q * 8;

    f32x4 acc[4][4] = {};
    for (int k0 = 0; k0 < KDIM; k0 += 32) {
        async_ld16(a_src0 + k0, lds_a);
        async_ld16(a_src1 + k0, lds_a + 4096);
        async_ld16(b_src0 + k0, lds_b);
        async_ld16(b_src1 + k0, lds_b + 4096);
        __syncthreads();
        bf16x8 af[4], bf[4];
#pragma unroll
        for (int f = 0; f < 4; ++f) {
            af[f] = *reinterpret_cast<const bf16x8*>(&s_a[a_base + f * 16 * 32]);
            bf[f] = *reinterpret_cast<const bf16x8*>(&s_b[b_base + f * 16 * 32]);
        }
#pragma unroll
        for (int fm = 0; fm < 4; ++fm)
#pragma unroll
            for (int fn = 0; fn < 4; ++fn)
                acc[fm][fn] = __builtin_amdgcn_mfma_f32_16x16x32_bf16(af[fm], bf[fn], acc[fm][fn], 0, 0, 0);
        __syncthreads();
    }

#pragma unroll
    for (int fn = 0; fn < 4; ++fn) {
        int n = n0 + wn * 64 + fn * 16 + lm;
        float bv = bias[e * BROWS + n];
#pragma unroll
        for (int fm = 0; fm < 4; ++fm) {
            int rbase = wm * 64 + fm * 16 + q * 4;
#pragma unroll
            for (int i = 0; i < 4; ++i) {
                int row = rbase + i;
                int slot = m0 + row;
                if (slot < cnt) {
                    float v = acc[fm][fn][i] + bv;
                    if (!PASS2) {
                        float sv = v / (1.f + __expf(-v));
                        Hbuf[((size_t)e * CAP + slot) * FFN_H + n] = (__bf16)sv;
                    } else {
                        atomicAdd(&out[(size_t)s_tok[row] * D_MODEL + n], s_wt[row] * v);
                    }
                }
            }
        }
    }
}

extern "C" void kernel_launch(void* const* d_in, const int* in_sizes, int n_in,
                              void* d_out, int out_size, void* d_ws, size_t ws_size,
                              hipStream_t stream) {
    const float* x  = (const float*)d_in[0];
    const float* rw = (const float*)d_in[1];
    const float* w1 = (const float*)d_in[2];
    const float* b1 = (const float*)d_in[3];
    const float* w2 = (const float*)d_in[4];
    const float* b2 = (const float*)d_in[5];
    float* out = (float*)d_out;

    char* ws = (char*)d_ws;
    __bf16* xb   = (__bf16*)(ws + XB_OFF);
    __bf16* w1b  = (__bf16*)(ws + W1B_OFF);
    __bf16* w2b  = (__bf16*)(ws + W2B_OFF);
    __bf16* hbuf = (__bf16*)(ws + HBUF_OFF);
    int*   counts = (int*)(ws + CNT_OFF);
    float* psum   = (float*)(ws + PSUM_OFF);
    int*   tok    = (int*)(ws + TOK_OFF);
    float* wt     = (float*)(ws + WT_OFF);

    hipMemsetAsync(out, 0, (size_t)out_size * sizeof(float), stream);
    hipMemsetAsync(ws + CNT_OFF, 0, 64, stream);

    {
        size_t n = (size_t)N_TOK * D_MODEL;
        cvt_bf16_kernel<<<(int)(n / 8 / 256), 256, 0, stream>>>(x, xb);
    }
    {
        size_t n = (size_t)N_EXPERTS * FFN_H * D_MODEL;
        cvt_bf16_kernel<<<(int)(n / 8 / 256), 256, 0, stream>>>(w1, w1b);
        cvt_bf16_kernel<<<(int)(n / 8 / 256), 256, 0, stream>>>(w2, w2b);
    }

    router_kernel<<<N_TOK / 4, 256, 0, stream>>>(x, rw, counts, psum, tok, wt);

    ffn_kernel<D_MODEL, false><<<dim3(FFN_H / 128, CAP / 128, N_EXPERTS), 256, 0, stream>>>(
        xb, w1b, b1, counts, tok, wt, hbuf, nullptr);
    ffn_kernel<FFN_H, true><<<dim3(D_MODEL / 128, CAP / 128, N_EXPERTS), 256, 0, stream>>>(
        hbuf, w2b, b2, counts, tok, wt, nullptr, out);

    aux_kernel<<<1, 64, 0, stream>>>(counts, psum, out + (size_t)N_TOK * D_MODEL);
}

// Round 3
// 384.392 us; speedup vs baseline: 1.3422x; 1.2143x over previous
//
#include <hip/hip_runtime.h>
#include <cstdint>
#include <cstddef>

#define D_MODEL 1024
#define N_EXPERTS 8
#define FFN_H 2048
#define N_TOK 4096
#define CAP 2048

typedef float f32x4 __attribute__((ext_vector_type(4)));
typedef __bf16 bf16x8 __attribute__((ext_vector_type(8)));

// ---- workspace layout (bytes) ----
static constexpr size_t XB_OFF   = 0;                          // [N_TOK][D] bf16
static constexpr size_t W1B_OFF  = XB_OFF  + (size_t)N_TOK * D_MODEL * 2;        // [E][H][D] bf16
static constexpr size_t W2B_OFF  = W1B_OFF + (size_t)N_EXPERTS * FFN_H * D_MODEL * 2; // [E][D][H] bf16
static constexpr size_t HBUF_OFF = W2B_OFF + (size_t)N_EXPERTS * D_MODEL * FFN_H * 2; // [E][CAP][H] bf16
static constexpr size_t CNT_OFF  = HBUF_OFF + (size_t)N_EXPERTS * CAP * FFN_H * 2;    // [E] int
static constexpr size_t PSUM_OFF = CNT_OFF + 32;               // [E] float
static constexpr size_t TOK_OFF  = PSUM_OFF + 32;              // [E][CAP] int
static constexpr size_t WT_OFF   = TOK_OFF + (size_t)N_EXPERTS * CAP * 4; // [E][CAP] float

// async global->LDS, 16 B per lane; LDS dest = wave-uniform base + lane*16
__device__ __forceinline__ void async_ld16(const void* g, void* l) {
    __builtin_amdgcn_global_load_lds(
        (const __attribute__((address_space(1))) unsigned int*)g,
        (__attribute__((address_space(3))) unsigned int*)l, 16, 0, 0);
}

// ---------------- fp32 -> bf16 conversion, 8 elems/thread ----------------
__global__ __launch_bounds__(256) void cvt_bf16_kernel(const float* __restrict__ src,
                                                       __bf16* __restrict__ dst) {
    size_t i = ((size_t)blockIdx.x * 256 + threadIdx.x) * 8;
    float4 a = *reinterpret_cast<const float4*>(src + i);
    float4 b = *reinterpret_cast<const float4*>(src + i + 4);
    bf16x8 r;
    r[0] = (__bf16)a.x; r[1] = (__bf16)a.y; r[2] = (__bf16)a.z; r[3] = (__bf16)a.w;
    r[4] = (__bf16)b.x; r[5] = (__bf16)b.y; r[6] = (__bf16)b.z; r[7] = (__bf16)b.w;
    *reinterpret_cast<bf16x8*>(dst + i) = r;
}

// ---------------- router: 64 blocks x 64 tokens, block-aggregated bucketing ----------------
__global__ __launch_bounds__(256) void router_kernel(const float* __restrict__ x,
                                                     const float* __restrict__ rw,
                                                     int* __restrict__ counts,
                                                     float* __restrict__ psum,
                                                     int* __restrict__ tok_list,
                                                     float* __restrict__ wt_list) {
    __shared__ float rws[N_EXPERTS * D_MODEL];   // 32 KB
    __shared__ int s_e0[64], s_e1[64], s_r0[64], s_r1[64];
    __shared__ float s_w0[64], s_w1[64];
    __shared__ int hist[N_EXPERTS], base[N_EXPERTS];
    __shared__ float pacc[N_EXPERTS];

    int tid = threadIdx.x;
    for (int i = tid * 4; i < N_EXPERTS * D_MODEL; i += 256 * 4)
        *reinterpret_cast<float4*>(&rws[i]) = *reinterpret_cast<const float4*>(&rw[i]);
    if (tid < N_EXPERTS) { hist[tid] = 0; pacc[tid] = 0.f; }
    __syncthreads();

    int wave = tid >> 6, lane = tid & 63;
    float psacc[8] = {0, 0, 0, 0, 0, 0, 0, 0};

    // each wave: 16 tokens sequentially
    for (int it = 0; it < 16; ++it) {
        int li = wave * 16 + it;                 // 0..63 local token
        int t = blockIdx.x * 64 + li;
        const float* xr = x + (size_t)t * D_MODEL;
        float acc[8] = {0, 0, 0, 0, 0, 0, 0, 0};
#pragma unroll
        for (int i = 0; i < D_MODEL / 64; ++i) {
            float xv = xr[lane + 64 * i];
#pragma unroll
            for (int e = 0; e < 8; ++e) acc[e] += xv * rws[e * D_MODEL + lane + 64 * i];
        }
        float logit[8];
#pragma unroll
        for (int e = 0; e < 8; ++e) {
            float v = acc[e];
            for (int off = 32; off; off >>= 1) v += __shfl_xor(v, off);
            logit[e] = v;                        // all lanes hold full sum
        }
        float mx = logit[0];
#pragma unroll
        for (int e = 1; e < 8; ++e) mx = fmaxf(mx, logit[e]);
        float p[8], s = 0.f;
#pragma unroll
        for (int e = 0; e < 8; ++e) { p[e] = expf(logit[e] - mx); s += p[e]; }
        float inv = 1.f / s;
#pragma unroll
        for (int e = 0; e < 8; ++e) { p[e] *= inv; psacc[e] += p[e]; }
        int e0 = 0; float p0 = p[0];
#pragma unroll
        for (int e = 1; e < 8; ++e) if (p[e] > p0) { p0 = p[e]; e0 = e; }
        int e1 = -1; float p1 = -1.f;
#pragma unroll
        for (int e = 0; e < 8; ++e) if (e != e0 && p[e] > p1) { p1 = p[e]; e1 = e; }
        float invw = 1.f / (p0 + p1);
        if (lane == 0) {
            s_e0[li] = e0; s_e1[li] = e1;
            s_w0[li] = p0 * invw; s_w1[li] = p1 * invw;
        }
    }
    if (lane == 0)
#pragma unroll
        for (int e = 0; e < 8; ++e) atomicAdd(&pacc[e], psacc[e]);
    __syncthreads();

    // block-local ranks via LDS atomics
    if (tid < 64) {
        s_r0[tid] = atomicAdd(&hist[s_e0[tid]], 1);
        s_r1[tid] = atomicAdd(&hist[s_e1[tid]], 1);
    }
    __syncthreads();
    // one global reservation per (block, expert)
    if (tid < N_EXPERTS) {
        base[tid] = atomicAdd(&counts[tid], hist[tid]);
        atomicAdd(&psum[tid], pacc[tid]);
    }
    __syncthreads();
    if (tid < 64) {
        int t = blockIdx.x * 64 + tid;
        int e0 = s_e0[tid], e1 = s_e1[tid];
        int q0 = base[e0] + s_r0[tid];
        if (q0 < CAP) { tok_list[e0 * CAP + q0] = t; wt_list[e0 * CAP + q0] = s_w0[tid]; }
        int q1 = base[e1] + s_r1[tid];
        if (q1 < CAP) { tok_list[e1 * CAP + q1] = t; wt_list[e1 * CAP + q1] = s_w1[tid]; }
    }
}

// ---------------- aux loss ----------------
__global__ void aux_kernel(const int* __restrict__ counts, const float* __restrict__ psum,
                           float* __restrict__ out_aux) {
    int lane = threadIdx.x;
    float v = 0.f;
    if (lane < 8)
        v = ((float)counts[lane] / (float)(N_TOK * 2)) * (psum[lane] / (float)N_TOK);
    for (int off = 32; off; off >>= 1) v += __shfl_xor(v, off);
    if (lane == 0) *out_aux = 8.f * v;
}

// ---------------- grouped GEMM, 128x128 tile, global_load_lds staging ----------------
template <int KDIM, bool PASS2>
__global__ __launch_bounds__(256) void ffn_kernel(const __bf16* __restrict__ A_base,
                                                  const __bf16* __restrict__ B_base,
                                                  const float* __restrict__ bias,
                                                  const int* __restrict__ counts,
                                                  const int* __restrict__ tok_list,
                                                  const float* __restrict__ wt_list,
                                                  __bf16* __restrict__ Hbuf,
                                                  float* __restrict__ out) {
    constexpr int BROWS = PASS2 ? D_MODEL : FFN_H;
    int e = blockIdx.z;
    int cnt = min(counts[e], CAP);
    int m0 = blockIdx.y * 128;
    if (m0 >= cnt) return;
    int n0 = blockIdx.x * 128;

    __shared__ __bf16 s_a[128 * 32];   // 8 KB, row-major, NO pad (global_load_lds)
    __shared__ __bf16 s_b[128 * 32];   // 8 KB
    __shared__ int s_tok[128];
    __shared__ float s_wt[128];

    int tid = threadIdx.x;
    if (tid < 128) {
        int slot = min(m0 + tid, cnt - 1);
        s_tok[tid] = tok_list[e * CAP + slot];
        s_wt[tid] = wt_list[e * CAP + slot];
    }
    __syncthreads();

    int colk = (tid & 3) * 8;
    const __bf16 *a_src0, *a_src1;
    if (PASS2) {
        int s0 = min(m0 + (tid >> 2), cnt - 1);
        int s1 = min(m0 + 64 + (tid >> 2), cnt - 1);
        a_src0 = A_base + ((size_t)e * CAP + s0) * KDIM + colk;
        a_src1 = A_base + ((size_t)e * CAP + s1) * KDIM + colk;
    } else {
        a_src0 = A_base + (size_t)s_tok[tid >> 2] * KDIM + colk;
        a_src1 = A_base + (size_t)s_tok[64 + (tid >> 2)] * KDIM + colk;
    }
    const __bf16* b_src0 = B_base + ((size_t)e * BROWS + n0 + (tid >> 2)) * KDIM + colk;
    const __bf16* b_src1 = b_src0 + (size_t)64 * KDIM;

    char* lds_a = (char*)s_a + (tid >> 6) * 1024;
    char* lds_b = (char*)s_b + (tid >> 6) * 1024;

    int wv = tid >> 6, lane = tid & 63;
    int wm = wv >> 1, wn = wv & 1;
    int lm = lane & 15, q = lane >> 4;
    int a_base = (wm * 64 + lm) * 32 + q * 8;
    int b_base = (wn * 64 + lm) * 32 + q * 8;

    f32x4 acc[4][4] = {};
    for (int k0 = 0; k0 < KDIM; k0 += 32) {
        async_ld16(a_src0 + k0, lds_a);
        async_ld16(a_src1 + k0, lds_a + 4096);
        async_ld16(b_src0 + k0, lds_b);
        async_ld16(b_src1 + k0, lds_b + 4096);
        __syncthreads();
        bf16x8 af[4], bf[4];
#pragma unroll
        for (int f = 0; f < 4; ++f) {
            af[f] = *reinterpret_cast<const bf16x8*>(&s_a[a_base + f * 16 * 32]);
            bf[f] = *reinterpret_cast<const bf16x8*>(&s_b[b_base + f * 16 * 32]);
        }
#pragma unroll
        for (int fm = 0; fm < 4; ++fm)
#pragma unroll
            for (int fn = 0; fn < 4; ++fn)
                acc[fm][fn] = __builtin_amdgcn_mfma_f32_16x16x32_bf16(af[fm], bf[fn], acc[fm][fn], 0, 0, 0);
        __syncthreads();
    }

#pragma unroll
    for (int fn = 0; fn < 4; ++fn) {
        int n = n0 + wn * 64 + fn * 16 + lm;
        float bv = bias[e * BROWS + n];
#pragma unroll
        for (int fm = 0; fm < 4; ++fm) {
            int rbase = wm * 64 + fm * 16 + q * 4;
#pragma unroll
            for (int i = 0; i < 4; ++i) {
                int row = rbase + i;
                int slot = m0 + row;
                if (slot < cnt) {
                    float v = acc[fm][fn][i] + bv;
                    if (!PASS2) {
                        float sv = v / (1.f + __expf(-v));
                        Hbuf[((size_t)e * CAP + slot) * FFN_H + n] = (__bf16)sv;
                    } else {
                        atomicAdd(&out[(size_t)s_tok[row] * D_MODEL + n], s_wt[row] * v);
                    }
                }
            }
        }
    }
}

extern "C" void kernel_launch(void* const* d_in, const int* in_sizes, int n_in,
                              void* d_out, int out_size, void* d_ws, size_t ws_size,
                              hipStream_t stream) {
    const float* x  = (const float*)d_in[0];
    const float* rw = (const float*)d_in[1];
    const float* w1 = (const float*)d_in[2];
    const float* b1 = (const float*)d_in[3];
    const float* w2 = (const float*)d_in[4];
    const float* b2 = (const float*)d_in[5];
    float* out = (float*)d_out;

    char* ws = (char*)d_ws;
    __bf16* xb   = (__bf16*)(ws + XB_OFF);
    __bf16* w1b  = (__bf16*)(ws + W1B_OFF);
    __bf16* w2b  = (__bf16*)(ws + W2B_OFF);
    __bf16* hbuf = (__bf16*)(ws + HBUF_OFF);
    int*   counts = (int*)(ws + CNT_OFF);
    float* psum   = (float*)(ws + PSUM_OFF);
    int*   tok    = (int*)(ws + TOK_OFF);
    float* wt     = (float*)(ws + WT_OFF);

    hipMemsetAsync(out, 0, (size_t)out_size * sizeof(float), stream);
    hipMemsetAsync(ws + CNT_OFF, 0, 64, stream);

    {
        size_t n = (size_t)N_TOK * D_MODEL;
        cvt_bf16_kernel<<<(int)(n / 8 / 256), 256, 0, stream>>>(x, xb);
    }
    {
        size_t n = (size_t)N_EXPERTS * FFN_H * D_MODEL;
        cvt_bf16_kernel<<<(int)(n / 8 / 256), 256, 0, stream>>>(w1, w1b);
        cvt_bf16_kernel<<<(int)(n / 8 / 256), 256, 0, stream>>>(w2, w2b);
    }

    router_kernel<<<N_TOK / 64, 256, 0, stream>>>(x, rw, counts, psum, tok, wt);

    ffn_kernel<D_MODEL, false><<<dim3(FFN_H / 128, CAP / 128, N_EXPERTS), 256, 0, stream>>>(
        xb, w1b, b1, counts, tok, wt, hbuf, nullptr);
    ffn_kernel<FFN_H, true><<<dim3(D_MODEL / 128, CAP / 128, N_EXPERTS), 256, 0, stream>>>(
        hbuf, w2b, b2, counts, tok, wt, nullptr, out);

    aux_kernel<<<1, 64, 0, stream>>>(counts, psum, out + (size_t)N_TOK * D_MODEL);
}

// Round 4
// 344.639 us; speedup vs baseline: 1.4970x; 1.1153x over previous
//
#include <hip/hip_runtime.h>
#include <cstdint>
#include <cstddef>

#define D_MODEL 1024
#define N_EXPERTS 8
#define FFN_H 2048
#define N_TOK 4096
#define CAP 2048

typedef float f32x4 __attribute__((ext_vector_type(4)));
typedef __bf16 bf16x8 __attribute__((ext_vector_type(8)));

// ---- workspace layout (bytes) ----
static constexpr size_t XB_OFF   = 0;                                                  // [N][D] bf16, 8 MB
static constexpr size_t W1B_OFF  = XB_OFF  + (size_t)N_TOK * D_MODEL * 2;              // 32 MB
static constexpr size_t W2B_OFF  = W1B_OFF + (size_t)N_EXPERTS * FFN_H * D_MODEL * 2;  // 32 MB
static constexpr size_t HBUF_OFF = W2B_OFF + (size_t)N_EXPERTS * D_MODEL * FFN_H * 2;  // [E][CAP][H] bf16, 64 MB
static constexpr size_t YBUF_OFF = HBUF_OFF + (size_t)N_EXPERTS * CAP * FFN_H * 2;     // [E][CAP][D] bf16, 32 MB
static constexpr size_t CNT_OFF  = YBUF_OFF + (size_t)N_EXPERTS * CAP * D_MODEL * 2;   // [E] int (64 B pad)
static constexpr size_t TOK_OFF  = CNT_OFF + 64;                                       // [E][CAP] int, 64 KB
static constexpr size_t TAE_OFF  = TOK_OFF + (size_t)N_EXPERTS * CAP * 4;              // [N] int (e0|e1<<16)
static constexpr size_t TAW_OFF  = TAE_OFF + (size_t)N_TOK * 4;                        // [N] float2
static constexpr size_t TAP_OFF  = TAW_OFF + (size_t)N_TOK * 8;                        // [N][8] float
static constexpr size_t TIX_OFF  = TAP_OFF + (size_t)N_TOK * 32;                       // [N] int2
static constexpr size_t TIW_OFF  = TIX_OFF + (size_t)N_TOK * 8;                        // [N] float2

// async global->LDS, 16 B per lane; LDS dest = wave-uniform base + lane*16
__device__ __forceinline__ void async_ld16(const void* g, void* l) {
    __builtin_amdgcn_global_load_lds(
        (const __attribute__((address_space(1))) unsigned int*)g,
        (__attribute__((address_space(3))) unsigned int*)l, 16, 0, 0);
}

// ---------------- fused fp32 -> bf16 conversion (x, w1, w2) ----------------
__global__ __launch_bounds__(256) void cvt_all_kernel(const float* __restrict__ x,
                                                      const float* __restrict__ w1,
                                                      const float* __restrict__ w2,
                                                      __bf16* __restrict__ xb,
                                                      __bf16* __restrict__ w1b,
                                                      __bf16* __restrict__ w2b) {
    int b = blockIdx.x;
    const float* src; __bf16* dst; size_t base;
    if (b < 2048)        { src = x;  dst = xb;  base = (size_t)b * 2048; }
    else if (b < 10240)  { src = w1; dst = w1b; base = (size_t)(b - 2048) * 2048; }
    else                 { src = w2; dst = w2b; base = (size_t)(b - 10240) * 2048; }
    size_t i = base + (size_t)threadIdx.x * 8;
    float4 a = *reinterpret_cast<const float4*>(src + i);
    float4 c = *reinterpret_cast<const float4*>(src + i + 4);
    bf16x8 r;
    r[0] = (__bf16)a.x; r[1] = (__bf16)a.y; r[2] = (__bf16)a.z; r[3] = (__bf16)a.w;
    r[4] = (__bf16)c.x; r[5] = (__bf16)c.y; r[6] = (__bf16)c.z; r[7] = (__bf16)c.w;
    *reinterpret_cast<bf16x8*>(dst + i) = r;
}

// ---------------- router phase A: logits + softmax + top2, one wave/token ----------------
__global__ __launch_bounds__(256) void logits_kernel(const float* __restrict__ x,
                                                     const float* __restrict__ rw,
                                                     int* __restrict__ counts,
                                                     int* __restrict__ tA_e,
                                                     float2* __restrict__ tA_w,
                                                     float* __restrict__ tA_p) {
    __shared__ float4 rws4[N_EXPERTS * D_MODEL / 4];   // 32 KB
    int tid = threadIdx.x;
    if (blockIdx.x == 0 && tid < 8) counts[tid] = 0;   // zeroed before bucket_kernel runs
    for (int i = tid; i < N_EXPERTS * D_MODEL / 4; i += 256)
        rws4[i] = reinterpret_cast<const float4*>(rw)[i];
    __syncthreads();

    int wave = tid >> 6, lane = tid & 63;
    int t = blockIdx.x * 4 + wave;
    const float4* xr = reinterpret_cast<const float4*>(x + (size_t)t * D_MODEL);
    float acc[8] = {};
#pragma unroll
    for (int i = 0; i < 4; ++i) {
        float4 xv = xr[lane + 64 * i];
#pragma unroll
        for (int e = 0; e < 8; ++e) {
            float4 wv = rws4[e * 256 + lane + 64 * i];
            acc[e] += xv.x * wv.x + xv.y * wv.y + xv.z * wv.z + xv.w * wv.w;
        }
    }
#pragma unroll
    for (int e = 0; e < 8; ++e)
        for (int off = 32; off; off >>= 1) acc[e] += __shfl_xor(acc[e], off);

    float mx = acc[0];
#pragma unroll
    for (int e = 1; e < 8; ++e) mx = fmaxf(mx, acc[e]);
    float p[8], s = 0.f;
#pragma unroll
    for (int e = 0; e < 8; ++e) { p[e] = expf(acc[e] - mx); s += p[e]; }
    float inv = 1.f / s;
#pragma unroll
    for (int e = 0; e < 8; ++e) p[e] *= inv;
    int e0 = 0; float p0 = p[0];
#pragma unroll
    for (int e = 1; e < 8; ++e) if (p[e] > p0) { p0 = p[e]; e0 = e; }
    int e1 = -1; float p1 = -1.f;
#pragma unroll
    for (int e = 0; e < 8; ++e) if (e != e0 && p[e] > p1) { p1 = p[e]; e1 = e; }
    float invw = 1.f / (p0 + p1);

    if (lane == 0) {
        tA_e[t] = e0 | (e1 << 16);
        tA_w[t] = make_float2(p0 * invw, p1 * invw);
#pragma unroll
        for (int e = 0; e < 8; ++e) tA_p[t * 8 + e] = p[e];
    }
}

// ---------------- router phase B: bucketing, 16 blocks x 256 tokens ----------------
__global__ __launch_bounds__(256) void bucket_kernel(const int* __restrict__ tA_e,
                                                     const float2* __restrict__ tA_w,
                                                     int* __restrict__ counts,
                                                     int* __restrict__ tok_list,
                                                     int2* __restrict__ tinfo_idx,
                                                     float2* __restrict__ tinfo_w) {
    __shared__ int hist[8], base[8];
    int tid = threadIdx.x;
    if (tid < 8) hist[tid] = 0;
    __syncthreads();
    int t = blockIdx.x * 256 + tid;
    int ee = tA_e[t];
    int e0 = ee & 0xffff, e1 = ee >> 16;
    int r0 = atomicAdd(&hist[e0], 1);
    int r1 = atomicAdd(&hist[e1], 1);
    __syncthreads();
    if (tid < 8) base[tid] = atomicAdd(&counts[tid], hist[tid]);
    __syncthreads();
    int q0 = min(base[e0] + r0, CAP - 1);
    int q1 = min(base[e1] + r1, CAP - 1);
    tok_list[e0 * CAP + q0] = t;
    tok_list[e1 * CAP + q1] = t;
    tinfo_idx[t] = make_int2(e0 * CAP + q0, e1 * CAP + q1);
    tinfo_w[t] = tA_w[t];
}

// ---------------- grouped GEMM, 128x128 tile, global_load_lds, XCD swizzle ----------------
// pass1: silu(x@w1^T + b1) -> Hbuf bf16 ; pass2: (h@w2^T + b2) -> Ybuf bf16 (no atomics)
template <int KDIM, bool PASS2>
__global__ __launch_bounds__(256) void ffn_kernel(const __bf16* __restrict__ A_base,
                                                  const __bf16* __restrict__ B_base,
                                                  const float* __restrict__ bias,
                                                  const int* __restrict__ counts,
                                                  const int* __restrict__ tok_list,
                                                  __bf16* __restrict__ Out_base) {
    constexpr int BROWS = PASS2 ? D_MODEL : FFN_H;
    constexpr int NT = BROWS / 128;
    // e fastest -> all blocks of expert e share an XCD; its 4 MB weights live in that L2
    int bid = blockIdx.x;
    int e = bid & 7;
    int r = bid >> 3;
    int n0 = (r % NT) * 128;
    int m0 = (r / NT) * 128;     // m slowest: early-exit tail at end of dispatch
    int cnt = min(counts[e], CAP);
    if (m0 >= cnt) return;

    __shared__ __bf16 s_a[128 * 32];   // 8 KB, row-major, NO pad (global_load_lds)
    __shared__ __bf16 s_b[128 * 32];
    __shared__ int s_tok[128];

    int tid = threadIdx.x;
    if (!PASS2 && tid < 128) {
        int slot = min(m0 + tid, cnt - 1);
        s_tok[tid] = tok_list[e * CAP + slot];
    }
    __syncthreads();

    int colk = (tid & 3) * 8;
    const __bf16 *a_src0, *a_src1;
    if (PASS2) {
        int s0 = min(m0 + (tid >> 2), cnt - 1);
        int s1 = min(m0 + 64 + (tid >> 2), cnt - 1);
        a_src0 = A_base + ((size_t)e * CAP + s0) * KDIM + colk;
        a_src1 = A_base + ((size_t)e * CAP + s1) * KDIM + colk;
    } else {
        a_src0 = A_base + (size_t)s_tok[tid >> 2] * KDIM + colk;
        a_src1 = A_base + (size_t)s_tok[64 + (tid >> 2)] * KDIM + colk;
    }
    const __bf16* b_src0 = B_base + ((size_t)e * BROWS + n0 + (tid >> 2)) * KDIM + colk;
    const __bf16* b_src1 = b_src0 + (size_t)64 * KDIM;

    char* lds_a = (char*)s_a + (tid >> 6) * 1024;
    char* lds_b = (char*)s_b + (tid >> 6) * 1024;

    int wv = tid >> 6, lane = tid & 63;
    int wm = wv >> 1, wn = wv & 1;
    int lm = lane & 15, q = lane >> 4;
    int a_base = (wm * 64 + lm) * 32 + q * 8;
    int b_base = (wn * 64 + lm) * 32 + q * 8;

    f32x4 acc[4][4] = {};
    for (int k0 = 0; k0 < KDIM; k0 += 32) {
        async_ld16(a_src0 + k0, lds_a);
        async_ld16(a_src1 + k0, lds_a + 4096);
        async_ld16(b_src0 + k0, lds_b);
        async_ld16(b_src1 + k0, lds_b + 4096);
        __syncthreads();
        bf16x8 af[4], bf[4];
#pragma unroll
        for (int f = 0; f < 4; ++f) {
            af[f] = *reinterpret_cast<const bf16x8*>(&s_a[a_base + f * 16 * 32]);
            bf[f] = *reinterpret_cast<const bf16x8*>(&s_b[b_base + f * 16 * 32]);
        }
#pragma unroll
        for (int fm = 0; fm < 4; ++fm)
#pragma unroll
            for (int fn = 0; fn < 4; ++fn)
                acc[fm][fn] = __builtin_amdgcn_mfma_f32_16x16x32_bf16(af[fm], bf[fn], acc[fm][fn], 0, 0, 0);
        __syncthreads();
    }

#pragma unroll
    for (int fn = 0; fn < 4; ++fn) {
        int n = n0 + wn * 64 + fn * 16 + lm;
        float bv = bias[e * BROWS + n];
#pragma unroll
        for (int fm = 0; fm < 4; ++fm) {
            int rbase = wm * 64 + fm * 16 + q * 4;
#pragma unroll
            for (int i = 0; i < 4; ++i) {
                int row = rbase + i;
                int slot = m0 + row;
                if (slot < cnt) {
                    float v = acc[fm][fn][i] + bv;
                    if (!PASS2) {
                        float sv = v / (1.f + __expf(-v));
                        Out_base[((size_t)e * CAP + slot) * FFN_H + n] = (__bf16)sv;
                    } else {
                        Out_base[((size_t)e * CAP + slot) * D_MODEL + n] = (__bf16)v;
                    }
                }
            }
        }
    }
}

// ---------------- combine: out[t] = w0*y[idx0] + w1*y[idx1]; block 0 also does aux ----------------
__global__ __launch_bounds__(256) void combine_kernel(const __bf16* __restrict__ ybuf,
                                                      const int2* __restrict__ tinfo_idx,
                                                      const float2* __restrict__ tinfo_w,
                                                      const int* __restrict__ counts,
                                                      const float* __restrict__ tA_p,
                                                      float* __restrict__ out) {
    int tid = threadIdx.x;
    if (blockIdx.x == 0) {
        __shared__ float pacc[8];
        if (tid < 8) pacc[tid] = 0.f;
        __syncthreads();
        float a[8] = {};
        for (int t = tid; t < N_TOK; t += 256) {
            const float4* pp = reinterpret_cast<const float4*>(tA_p + (size_t)t * 8);
            float4 u = pp[0], v = pp[1];
            a[0] += u.x; a[1] += u.y; a[2] += u.z; a[3] += u.w;
            a[4] += v.x; a[5] += v.y; a[6] += v.z; a[7] += v.w;
        }
#pragma unroll
        for (int e = 0; e < 8; ++e) atomicAdd(&pacc[e], a[e]);
        __syncthreads();
        if (tid == 0) {
            float s = 0.f;
#pragma unroll
            for (int e = 0; e < 8; ++e)
                s += ((float)counts[e] / (float)(N_TOK * 2)) * (pacc[e] / (float)N_TOK);
            out[(size_t)N_TOK * D_MODEL] = 8.f * s;
        }
    }
    int t = blockIdx.x * 2 + (tid >> 7);
    int d0 = (tid & 127) * 8;
    int2 ix = tinfo_idx[t];
    float2 w = tinfo_w[t];
    bf16x8 ya = *reinterpret_cast<const bf16x8*>(ybuf + (size_t)ix.x * D_MODEL + d0);
    bf16x8 yb = *reinterpret_cast<const bf16x8*>(ybuf + (size_t)ix.y * D_MODEL + d0);
    float4 o0, o1;
    o0.x = w.x * (float)ya[0] + w.y * (float)yb[0];
    o0.y = w.x * (float)ya[1] + w.y * (float)yb[1];
    o0.z = w.x * (float)ya[2] + w.y * (float)yb[2];
    o0.w = w.x * (float)ya[3] + w.y * (float)yb[3];
    o1.x = w.x * (float)ya[4] + w.y * (float)yb[4];
    o1.y = w.x * (float)ya[5] + w.y * (float)yb[5];
    o1.z = w.x * (float)ya[6] + w.y * (float)yb[6];
    o1.w = w.x * (float)ya[7] + w.y * (float)yb[7];
    float* op = out + (size_t)t * D_MODEL + d0;
    *reinterpret_cast<float4*>(op) = o0;
    *reinterpret_cast<float4*>(op + 4) = o1;
}

extern "C" void kernel_launch(void* const* d_in, const int* in_sizes, int n_in,
                              void* d_out, int out_size, void* d_ws, size_t ws_size,
                              hipStream_t stream) {
    const float* x  = (const float*)d_in[0];
    const float* rw = (const float*)d_in[1];
    const float* w1 = (const float*)d_in[2];
    const float* b1 = (const float*)d_in[3];
    const float* w2 = (const float*)d_in[4];
    const float* b2 = (const float*)d_in[5];
    float* out = (float*)d_out;

    char* ws = (char*)d_ws;
    __bf16* xb    = (__bf16*)(ws + XB_OFF);
    __bf16* w1b   = (__bf16*)(ws + W1B_OFF);
    __bf16* w2b   = (__bf16*)(ws + W2B_OFF);
    __bf16* hbuf  = (__bf16*)(ws + HBUF_OFF);
    __bf16* ybuf  = (__bf16*)(ws + YBUF_OFF);
    int*    counts = (int*)(ws + CNT_OFF);
    int*    tok    = (int*)(ws + TOK_OFF);
    int*    tA_e   = (int*)(ws + TAE_OFF);
    float2* tA_w   = (float2*)(ws + TAW_OFF);
    float*  tA_p   = (float*)(ws + TAP_OFF);
    int2*   tix    = (int2*)(ws + TIX_OFF);
    float2* tiw    = (float2*)(ws + TIW_OFF);

    cvt_all_kernel<<<18432, 256, 0, stream>>>(x, w1, w2, xb, w1b, w2b);
    logits_kernel<<<N_TOK / 4, 256, 0, stream>>>(x, rw, counts, tA_e, tA_w, tA_p);
    bucket_kernel<<<N_TOK / 256, 256, 0, stream>>>(tA_e, tA_w, counts, tok, tix, tiw);

    ffn_kernel<D_MODEL, false><<<8 * (FFN_H / 128) * (CAP / 128), 256, 0, stream>>>(
        xb, w1b, b1, counts, tok, hbuf);
    ffn_kernel<FFN_H, true><<<8 * (D_MODEL / 128) * (CAP / 128), 256, 0, stream>>>(
        hbuf, w2b, b2, counts, tok, ybuf);

    combine_kernel<<<N_TOK / 2, 256, 0, stream>>>(ybuf, tix, tiw, counts, tA_p, out);
}

// Round 5
// 305.496 us; speedup vs baseline: 1.6888x; 1.1281x over previous
//
#include <hip/hip_runtime.h>
#include <cstdint>
#include <cstddef>

#define D_MODEL 1024
#define N_EXPERTS 8
#define FFN_H 2048
#define N_TOK 4096
#define CAP 2048

typedef float f32x4 __attribute__((ext_vector_type(4)));
typedef __bf16 bf16x8 __attribute__((ext_vector_type(8)));

// ---- workspace layout (bytes) ----
static constexpr size_t XB_OFF   = 0;                                                  // [N][D] bf16
static constexpr size_t W1B_OFF  = XB_OFF  + (size_t)N_TOK * D_MODEL * 2;
static constexpr size_t W2B_OFF  = W1B_OFF + (size_t)N_EXPERTS * FFN_H * D_MODEL * 2;
static constexpr size_t HBUF_OFF = W2B_OFF + (size_t)N_EXPERTS * D_MODEL * FFN_H * 2;  // [E][CAP][H] bf16
static constexpr size_t YBUF_OFF = HBUF_OFF + (size_t)N_EXPERTS * CAP * FFN_H * 2;     // [E][CAP][D] bf16
static constexpr size_t CNT_OFF  = YBUF_OFF + (size_t)N_EXPERTS * CAP * D_MODEL * 2;   // [8] int
static constexpr size_t PSUM_OFF = CNT_OFF + 32;                                       // [8] float
static constexpr size_t TOK_OFF  = PSUM_OFF + 32;                                      // [E][CAP] int
static constexpr size_t TIX_OFF  = TOK_OFF + (size_t)N_EXPERTS * CAP * 4;              // [N] int2
static constexpr size_t TIW_OFF  = TIX_OFF + (size_t)N_TOK * 8;                        // [N] float2

// async global->LDS, 16 B per lane; LDS dest = wave-uniform base + lane*16
__device__ __forceinline__ void async_ld16(const void* g, void* l) {
    __builtin_amdgcn_global_load_lds(
        (const __attribute__((address_space(1))) unsigned int*)g,
        (__attribute__((address_space(3))) unsigned int*)l, 16, 0, 0);
}

// ---------------- fused prep: blocks 0..63 = router; 64.. = fp32->bf16 cvt ----------------
__global__ __launch_bounds__(256) void prep_kernel(const float* __restrict__ x,
                                                   const float* __restrict__ rw,
                                                   const float* __restrict__ w1,
                                                   const float* __restrict__ w2,
                                                   __bf16* __restrict__ xb,
                                                   __bf16* __restrict__ w1b,
                                                   __bf16* __restrict__ w2b,
                                                   int* __restrict__ counts,
                                                   float* __restrict__ psum,
                                                   int* __restrict__ tok_list,
                                                   int2* __restrict__ tinfo_idx,
                                                   float2* __restrict__ tinfo_w) {
    __shared__ float rws[N_EXPERTS * D_MODEL];   // 32 KB (router blocks only)
    __shared__ int s_e0[64], s_e1[64], s_r0[64], s_r1[64];
    __shared__ float s_w0[64], s_w1[64];
    __shared__ int hist[8], base[8];
    __shared__ float pacc[8];

    int tid = threadIdx.x;
    int b = blockIdx.x;
    if (b >= 64) {
        // ---- conversion path ----
        int c = b - 64;
        const float* src; __bf16* dst; size_t bb;
        if (c < 2048)       { src = x;  dst = xb;  bb = (size_t)c * 2048; }
        else if (c < 10240) { src = w1; dst = w1b; bb = (size_t)(c - 2048) * 2048; }
        else                { src = w2; dst = w2b; bb = (size_t)(c - 10240) * 2048; }
        size_t i = bb + (size_t)tid * 8;
        float4 a = *reinterpret_cast<const float4*>(src + i);
        float4 d = *reinterpret_cast<const float4*>(src + i + 4);
        bf16x8 r;
        r[0] = (__bf16)a.x; r[1] = (__bf16)a.y; r[2] = (__bf16)a.z; r[3] = (__bf16)a.w;
        r[4] = (__bf16)d.x; r[5] = (__bf16)d.y; r[6] = (__bf16)d.z; r[7] = (__bf16)d.w;
        *reinterpret_cast<bf16x8*>(dst + i) = r;
        return;
    }

    // ---- router path: 64 tokens per block ----
    for (int i = tid * 4; i < N_EXPERTS * D_MODEL; i += 256 * 4)
        *reinterpret_cast<float4*>(&rws[i]) = *reinterpret_cast<const float4*>(&rw[i]);
    if (tid < 8) { hist[tid] = 0; pacc[tid] = 0.f; }
    __syncthreads();

    int wave = tid >> 6, lane = tid & 63;
    float psacc[8] = {};
    for (int it = 0; it < 16; ++it) {
        int li = wave * 16 + it;
        int t = b * 64 + li;
        const float* xr = x + (size_t)t * D_MODEL;
        float acc[8] = {};
#pragma unroll
        for (int i = 0; i < D_MODEL / 64; ++i) {
            float xv = xr[lane + 64 * i];
#pragma unroll
            for (int e = 0; e < 8; ++e) acc[e] += xv * rws[e * D_MODEL + lane + 64 * i];
        }
        float logit[8];
#pragma unroll
        for (int e = 0; e < 8; ++e) {
            float v = acc[e];
            for (int off = 32; off; off >>= 1) v += __shfl_xor(v, off);
            logit[e] = v;
        }
        float mx = logit[0];
#pragma unroll
        for (int e = 1; e < 8; ++e) mx = fmaxf(mx, logit[e]);
        float p[8], s = 0.f;
#pragma unroll
        for (int e = 0; e < 8; ++e) { p[e] = expf(logit[e] - mx); s += p[e]; }
        float inv = 1.f / s;
#pragma unroll
        for (int e = 0; e < 8; ++e) { p[e] *= inv; psacc[e] += p[e]; }
        int e0 = 0; float p0 = p[0];
#pragma unroll
        for (int e = 1; e < 8; ++e) if (p[e] > p0) { p0 = p[e]; e0 = e; }
        int e1 = -1; float p1 = -1.f;
#pragma unroll
        for (int e = 0; e < 8; ++e) if (e != e0 && p[e] > p1) { p1 = p[e]; e1 = e; }
        float invw = 1.f / (p0 + p1);
        if (lane == 0) {
            s_e0[li] = e0; s_e1[li] = e1;
            s_w0[li] = p0 * invw; s_w1[li] = p1 * invw;
        }
    }
    if (lane == 0)
#pragma unroll
        for (int e = 0; e < 8; ++e) atomicAdd(&pacc[e], psacc[e]);
    __syncthreads();

    if (tid < 64) {
        s_r0[tid] = atomicAdd(&hist[s_e0[tid]], 1);
        s_r1[tid] = atomicAdd(&hist[s_e1[tid]], 1);
    }
    __syncthreads();
    if (tid < 8) {
        base[tid] = atomicAdd(&counts[tid], hist[tid]);   // device-scope, 512 total
        atomicAdd(&psum[tid], pacc[tid]);
    }
    __syncthreads();
    if (tid < 64) {
        int t = b * 64 + tid;
        int e0 = s_e0[tid], e1 = s_e1[tid];
        int q0 = min(base[e0] + s_r0[tid], CAP - 1);
        int q1 = min(base[e1] + s_r1[tid], CAP - 1);
        tok_list[e0 * CAP + q0] = t;
        tok_list[e1 * CAP + q1] = t;
        tinfo_idx[t] = make_int2(e0 * CAP + q0, e1 * CAP + q1);
        tinfo_w[t] = make_float2(s_w0[tid], s_w1[tid]);
    }
}

// ---------------- grouped GEMM, 128x128 tile, BK=64, global_load_lds, XCD swizzle ----------------
template <int KDIM, bool PASS2>
__global__ __launch_bounds__(256, 4) void ffn_kernel(const __bf16* __restrict__ A_base,
                                                     const __bf16* __restrict__ B_base,
                                                     const float* __restrict__ bias,
                                                     const int* __restrict__ counts,
                                                     const int* __restrict__ tok_list,
                                                     __bf16* __restrict__ Out_base) {
    constexpr int BROWS = PASS2 ? D_MODEL : FFN_H;
    constexpr int NT = BROWS / 128;
    int bid = blockIdx.x;
    int e = bid & 7;                 // expert fastest -> XCD-pinned weights
    int r = bid >> 3;
    int n0 = (r % NT) * 128;
    int m0 = (r / NT) * 128;
    int cnt = min(counts[e], CAP);
    if (m0 >= cnt) return;

    // two 128x32 halves per operand (k-lo / k-hi), staged like BK=32 -> same bank pattern
    __shared__ __bf16 s_a[2][128 * 32];   // 16 KB
    __shared__ __bf16 s_b[2][128 * 32];   // 16 KB
    __shared__ int s_tok[128];

    int tid = threadIdx.x;
    if (!PASS2 && tid < 128) {
        int slot = min(m0 + tid, cnt - 1);
        s_tok[tid] = tok_list[e * CAP + slot];
    }
    __syncthreads();

    int colk = (tid & 3) * 8;
    const __bf16 *a_src0, *a_src1;
    if (PASS2) {
        int s0 = min(m0 + (tid >> 2), cnt - 1);
        int s1 = min(m0 + 64 + (tid >> 2), cnt - 1);
        a_src0 = A_base + ((size_t)e * CAP + s0) * KDIM + colk;
        a_src1 = A_base + ((size_t)e * CAP + s1) * KDIM + colk;
    } else {
        a_src0 = A_base + (size_t)s_tok[tid >> 2] * KDIM + colk;
        a_src1 = A_base + (size_t)s_tok[64 + (tid >> 2)] * KDIM + colk;
    }
    const __bf16* b_src0 = B_base + ((size_t)e * BROWS + n0 + (tid >> 2)) * KDIM + colk;
    const __bf16* b_src1 = b_src0 + (size_t)64 * KDIM;

    char* lds_a = (char*)&s_a[0][0] + (tid >> 6) * 1024;
    char* lds_b = (char*)&s_b[0][0] + (tid >> 6) * 1024;

    int wv = tid >> 6, lane = tid & 63;
    int wm = wv >> 1, wn = wv & 1;
    int lm = lane & 15, q = lane >> 4;
    int a_base = (wm * 64 + lm) * 32 + q * 8;
    int b_base = (wn * 64 + lm) * 32 + q * 8;

    f32x4 acc[4][4] = {};
    for (int k0 = 0; k0 < KDIM; k0 += 64) {
        // A rows 0-63 & 64-127, k-lo half then k-hi half; same for B
        async_ld16(a_src0 + k0,      lds_a);
        async_ld16(a_src1 + k0,      lds_a + 4096);
        async_ld16(a_src0 + k0 + 32, lds_a + 8192);
        async_ld16(a_src1 + k0 + 32, lds_a + 8192 + 4096);
        async_ld16(b_src0 + k0,      lds_b);
        async_ld16(b_src1 + k0,      lds_b + 4096);
        async_ld16(b_src0 + k0 + 32, lds_b + 8192);
        async_ld16(b_src1 + k0 + 32, lds_b + 8192 + 4096);
        __syncthreads();
#pragma unroll
        for (int kk = 0; kk < 2; ++kk) {
            bf16x8 af[4], bf[4];
#pragma unroll
            for (int f = 0; f < 4; ++f) {
                af[f] = *reinterpret_cast<const bf16x8*>(&s_a[kk][a_base + f * 16 * 32]);
                bf[f] = *reinterpret_cast<const bf16x8*>(&s_b[kk][b_base + f * 16 * 32]);
            }
#pragma unroll
            for (int fm = 0; fm < 4; ++fm)
#pragma unroll
                for (int fn = 0; fn < 4; ++fn)
                    acc[fm][fn] = __builtin_amdgcn_mfma_f32_16x16x32_bf16(af[fm], bf[fn], acc[fm][fn], 0, 0, 0);
        }
        __syncthreads();
    }

#pragma unroll
    for (int fn = 0; fn < 4; ++fn) {
        int n = n0 + wn * 64 + fn * 16 + lm;
        float bv = bias[e * BROWS + n];
#pragma unroll
        for (int fm = 0; fm < 4; ++fm) {
            int rbase = wm * 64 + fm * 16 + q * 4;
#pragma unroll
            for (int i = 0; i < 4; ++i) {
                int row = rbase + i;
                int slot = m0 + row;
                if (slot < cnt) {
                    float v = acc[fm][fn][i] + bv;
                    if (!PASS2) {
                        float sv = v / (1.f + __expf(-v));
                        Out_base[((size_t)e * CAP + slot) * FFN_H + n] = (__bf16)sv;
                    } else {
                        Out_base[((size_t)e * CAP + slot) * D_MODEL + n] = (__bf16)v;
                    }
                }
            }
        }
    }
}

// ---------------- combine: out[t] = w0*y[idx0] + w1*y[idx1]; block 0 thread 0 does aux ----------------
__global__ __launch_bounds__(256) void combine_kernel(const __bf16* __restrict__ ybuf,
                                                      const int2* __restrict__ tinfo_idx,
                                                      const float2* __restrict__ tinfo_w,
                                                      const int* __restrict__ counts,
                                                      const float* __restrict__ psum,
                                                      float* __restrict__ out) {
    int tid = threadIdx.x;
    if (blockIdx.x == 0 && tid == 0) {
        float s = 0.f;
#pragma unroll
        for (int e = 0; e < 8; ++e)
            s += ((float)counts[e] / (float)(N_TOK * 2)) * (psum[e] / (float)N_TOK);
        out[(size_t)N_TOK * D_MODEL] = 8.f * s;
    }
    int t = blockIdx.x * 2 + (tid >> 7);
    int d0 = (tid & 127) * 8;
    int2 ix = tinfo_idx[t];
    float2 w = tinfo_w[t];
    bf16x8 ya = *reinterpret_cast<const bf16x8*>(ybuf + (size_t)ix.x * D_MODEL + d0);
    bf16x8 yb = *reinterpret_cast<const bf16x8*>(ybuf + (size_t)ix.y * D_MODEL + d0);
    float4 o0, o1;
    o0.x = w.x * (float)ya[0] + w.y * (float)yb[0];
    o0.y = w.x * (float)ya[1] + w.y * (float)yb[1];
    o0.z = w.x * (float)ya[2] + w.y * (float)yb[2];
    o0.w = w.x * (float)ya[3] + w.y * (float)yb[3];
    o1.x = w.x * (float)ya[4] + w.y * (float)yb[4];
    o1.y = w.x * (float)ya[5] + w.y * (float)yb[5];
    o1.z = w.x * (float)ya[6] + w.y * (float)yb[6];
    o1.w = w.x * (float)ya[7] + w.y * (float)yb[7];
    float* op = out + (size_t)t * D_MODEL + d0;
    *reinterpret_cast<float4*>(op) = o0;
    *reinterpret_cast<float4*>(op + 4) = o1;
}

extern "C" void kernel_launch(void* const* d_in, const int* in_sizes, int n_in,
                              void* d_out, int out_size, void* d_ws, size_t ws_size,
                              hipStream_t stream) {
    const float* x  = (const float*)d_in[0];
    const float* rw = (const float*)d_in[1];
    const float* w1 = (const float*)d_in[2];
    const float* b1 = (const float*)d_in[3];
    const float* w2 = (const float*)d_in[4];
    const float* b2 = (const float*)d_in[5];
    float* out = (float*)d_out;

    char* ws = (char*)d_ws;
    __bf16* xb     = (__bf16*)(ws + XB_OFF);
    __bf16* w1b    = (__bf16*)(ws + W1B_OFF);
    __bf16* w2b    = (__bf16*)(ws + W2B_OFF);
    __bf16* hbuf   = (__bf16*)(ws + HBUF_OFF);
    __bf16* ybuf   = (__bf16*)(ws + YBUF_OFF);
    int*    counts = (int*)(ws + CNT_OFF);
    float*  psum   = (float*)(ws + PSUM_OFF);
    int*    tok    = (int*)(ws + TOK_OFF);
    int2*   tix    = (int2*)(ws + TIX_OFF);
    float2* tiw    = (float2*)(ws + TIW_OFF);

    hipMemsetAsync(ws + CNT_OFF, 0, 64, stream);   // counts + psum

    prep_kernel<<<64 + 18432, 256, 0, stream>>>(x, rw, w1, w2, xb, w1b, w2b,
                                                counts, psum, tok, tix, tiw);

    ffn_kernel<D_MODEL, false><<<8 * (FFN_H / 128) * (CAP / 128), 256, 0, stream>>>(
        xb, w1b, b1, counts, tok, hbuf);
    ffn_kernel<FFN_H, true><<<8 * (D_MODEL / 128) * (CAP / 128), 256, 0, stream>>>(
        hbuf, w2b, b2, counts, tok, ybuf);

    combine_kernel<<<N_TOK / 2, 256, 0, stream>>>(ybuf, tix, tiw, counts, psum, out);
}